// Round 6
// baseline (463.264 us; speedup 1.0000x reference)
//
#include <hip/hip_runtime.h>

// GraphConvolutionDiagLayer: out[dst[e]] += ew[e] * (x[src[e]] * W)
// N=10000, E=640000, F=128, fp32.
//
// Round 6: eliminate per-edge global atomics (rounds 3-5 evidence: 640K
// device-scope atomicAdds = ~20MB fabric write traffic + round-trips that
// XCD slicing cannot remove).
//   K1 convert: xb[n*64+j] = pack2(bf16(x[n,j]*W[j]), bf16(x[n,j+64]*W[j+64]))
//               (2.56MB, L2-resident); zeroes g_cnt/spill_cnt.
//   K2 sort:    block counting-sort of 2048-edge tiles into NB=256 dst-range
//               buckets via LDS hist+scan+reorder; ONE global atomic per
//               (tile,bucket) (~80K total); coalesced record stores.
//               Record = 8B: lo = src | dl<<14 | b<<21, hi = fp32 w.
//   K3 acc:     one 512-thread block per bucket; fp32 acc[R=40][128] in LDS;
//               per record: uniform 8B load, 256B xb row gather (L2),
//               2x ds_add_f32 (2-way bank = free); dense single write of out.
//   Spill list keeps correctness independent of cap; fallback if ws/N bad.

#define F_DIM 128
#define NB 256
#define TILE 2048
#define SPILL_CAP 8192
#define R_MAX 64

__device__ __forceinline__ unsigned f2bf_bits(float f)
{
    unsigned u = __float_as_uint(f);
    return (u + 0x7FFFu + ((u >> 16) & 1u)) >> 16;   // RNE to bf16
}

__global__ void __launch_bounds__(256)
convert_kernel(const float* __restrict__ x, const float* __restrict__ W,
               unsigned* __restrict__ xb, int* __restrict__ g_cnt,
               int* __restrict__ spill_cnt, int NU)
{
    int t = blockIdx.x * 256 + threadIdx.x;
    if (t < NU) {
        int n = t >> 6, j = t & 63;
        float v0 = x[n * F_DIM + j]      * W[j];
        float v1 = x[n * F_DIM + j + 64] * W[j + 64];
        xb[t] = f2bf_bits(v0) | (f2bf_bits(v1) << 16);
    }
    if (t < NB) g_cnt[t] = 0;
    if (t == NB) *spill_cnt = 0;
}

__global__ void __launch_bounds__(256)
sort_kernel(const int* __restrict__ src, const int* __restrict__ dst,
            const float* __restrict__ ew,
            int* __restrict__ g_cnt, int* __restrict__ spill_cnt,
            int4* __restrict__ spill, uint2* __restrict__ segs,
            int E, unsigned M, int R, int cap)
{
    __shared__ unsigned reo_lo[TILE];
    __shared__ unsigned reo_hi[TILE];
    __shared__ int hist[NB], scn[NB], gbase[NB];

    int tid = threadIdx.x;
    int tile0 = blockIdx.x * TILE;
    int tcnt = E - tile0; if (tcnt > TILE) tcnt = TILE;

    if (tid < NB) hist[tid] = 0;
    __syncthreads();

    int b_k[8], rank_k[8]; unsigned lo_k[8], w_k[8];
    int kmax = 0;
    #pragma unroll
    for (int k = 0; k < 8; ++k) {
        int e = tile0 + k * 256 + tid;
        if (e < E) {
            int d = dst[e];
            int b = (int)__umulhi((unsigned)d, M);     // d / R (exact, d<2^16)
            int dl = d - b * R;
            b_k[kmax]    = b;
            lo_k[kmax]   = ((unsigned)src[e] & 0x3FFFu) | ((unsigned)dl << 14)
                         | ((unsigned)b << 21);
            w_k[kmax]    = __float_as_uint(ew[e]);
            rank_k[kmax] = atomicAdd(&hist[b], 1);     // LDS atomic
            ++kmax;
        }
    }
    __syncthreads();

    if (tid < NB) scn[tid] = hist[tid];
    __syncthreads();
    for (int d = 1; d < NB; d <<= 1) {
        int v = 0;
        if (tid < NB && tid >= d) v = scn[tid - d];
        __syncthreads();
        if (tid < NB) scn[tid] += v;                    // inclusive scan
        __syncthreads();
    }

    for (int k = 0; k < kmax; ++k) {
        int b = b_k[k];
        int pos = (scn[b] - hist[b]) + rank_k[k];       // excl offset + rank
        reo_lo[pos] = lo_k[k];
        reo_hi[pos] = w_k[k];
    }
    if (tid < NB)
        gbase[tid] = hist[tid] ? atomicAdd(&g_cnt[tid], hist[tid]) : 0;
    __syncthreads();

    for (int p = tid; p < tcnt; p += 256) {
        unsigned lo = reo_lo[p];
        int b = (int)(lo >> 21);
        int slot = gbase[b] + (p - (scn[b] - hist[b]));
        if (slot < cap) {
            segs[(size_t)b * cap + slot] = make_uint2(lo, reo_hi[p]);
        } else {
            int sp = atomicAdd(spill_cnt, 1);
            if (sp < SPILL_CAP) {
                int dl = (int)((lo >> 14) & 0x7Fu);
                spill[sp] = make_int4(b * R + dl, (int)(lo & 0x3FFFu),
                                      (int)reo_hi[p], 0);
            }
        }
    }
}

__device__ __forceinline__ void acc_record(float* __restrict__ acc,
                                           unsigned lo, unsigned rv,
                                           float w, int lane)
{
    int dl = (int)((lo >> 14) & 0x7Fu);
    float vlo = __uint_as_float(rv << 16);
    float vhi = __uint_as_float(rv & 0xFFFF0000u);
    atomicAdd(&acc[dl * F_DIM + lane],      w * vlo);
    atomicAdd(&acc[dl * F_DIM + 64 + lane], w * vhi);
}

__global__ void __launch_bounds__(512)
acc_kernel(const unsigned* __restrict__ xb, const int* __restrict__ g_cnt,
           const int* __restrict__ spill_cnt, const int4* __restrict__ spill,
           const uint2* __restrict__ segs, float* __restrict__ out,
           int N, int R, int cap)
{
    __shared__ float acc[R_MAX * F_DIM];
    int b    = blockIdx.x;
    int tid  = threadIdx.x;
    int lane = tid & 63;
    int wid  = tid >> 6;                 // 0..7
    int rows = N - b * R; if (rows > R) rows = R;
    if (rows <= 0) return;

    for (int i = tid; i < rows * F_DIM; i += 512) acc[i] = 0.f;
    __syncthreads();

    int cnt = g_cnt[b]; if (cnt > cap) cnt = cap;
    const uint2* seg = segs + (size_t)b * cap;
    int chunk = (cnt + 7) >> 3;
    int r0 = wid * chunk;
    int r1 = r0 + chunk; if (r1 > cnt) r1 = cnt;

    int r = r0;
    for (; r + 4 <= r1; r += 4) {
        uint2 q0 = seg[r], q1 = seg[r + 1], q2 = seg[r + 2], q3 = seg[r + 3];
        unsigned rv0 = xb[(size_t)(q0.x & 0x3FFFu) * 64 + lane];
        unsigned rv1 = xb[(size_t)(q1.x & 0x3FFFu) * 64 + lane];
        unsigned rv2 = xb[(size_t)(q2.x & 0x3FFFu) * 64 + lane];
        unsigned rv3 = xb[(size_t)(q3.x & 0x3FFFu) * 64 + lane];
        acc_record(acc, q0.x, rv0, __uint_as_float(q0.y), lane);
        acc_record(acc, q1.x, rv1, __uint_as_float(q1.y), lane);
        acc_record(acc, q2.x, rv2, __uint_as_float(q2.y), lane);
        acc_record(acc, q3.x, rv3, __uint_as_float(q3.y), lane);
    }
    for (; r < r1; ++r) {
        uint2 q = seg[r];
        unsigned rv = xb[(size_t)(q.x & 0x3FFFu) * 64 + lane];
        acc_record(acc, q.x, rv, __uint_as_float(q.y), lane);
    }
    __syncthreads();

    // spill fold-in (normally empty)
    if (wid == 0) {
        int sc = *spill_cnt; if (sc > SPILL_CAP) sc = SPILL_CAP;
        for (int t = 0; t < sc; ++t) {
            int4 sp = spill[t];
            if (sp.x >= b * R && sp.x < b * R + rows) {
                unsigned rv = xb[(size_t)sp.y * 64 + lane];
                float w = __int_as_float(sp.z);
                int dl = sp.x - b * R;
                float vlo = __uint_as_float(rv << 16);
                float vhi = __uint_as_float(rv & 0xFFFF0000u);
                atomicAdd(&acc[dl * F_DIM + lane],      w * vlo);
                atomicAdd(&acc[dl * F_DIM + 64 + lane], w * vhi);
            }
        }
    }
    __syncthreads();

    float* ob = out + (size_t)b * R * F_DIM;
    for (int i = tid; i < rows * F_DIM; i += 512) ob[i] = acc[i];
}

// ---- fallback: direct fp32 atomic scatter ----
__global__ void __launch_bounds__(256)
fallback_scatter(const float* __restrict__ x, const float* __restrict__ W,
                 const float* __restrict__ ew, const int* __restrict__ src,
                 const int* __restrict__ dst, float* __restrict__ out, int E)
{
    int t = blockIdx.x * 256 + threadIdx.x;
    int e = t >> 5;
    if (e >= E) return;
    int f4 = t & 31;
    int   s = src[e];
    int   d = dst[e];
    float w = ew[e];
    float4 xv = reinterpret_cast<const float4*>(x)[s * 32 + f4];
    float4 wv = reinterpret_cast<const float4*>(W)[f4];
    float* o = out + d * F_DIM + f4 * 4;
    unsafeAtomicAdd(o + 0, xv.x * wv.x * w);
    unsafeAtomicAdd(o + 1, xv.y * wv.y * w);
    unsafeAtomicAdd(o + 2, xv.z * wv.z * w);
    unsafeAtomicAdd(o + 3, xv.w * wv.w * w);
}

extern "C" void kernel_launch(void* const* d_in, const int* in_sizes, int n_in,
                              void* d_out, int out_size, void* d_ws, size_t ws_size,
                              hipStream_t stream)
{
    const float* x   = (const float*)d_in[0];
    const float* W   = (const float*)d_in[1];
    const float* ew  = (const float*)d_in[2];
    const int*   src = (const int*)d_in[3];
    const int*   dst = (const int*)d_in[4];
    float*       out = (float*)d_out;

    const int E  = in_sizes[2];
    const int N  = out_size / F_DIM;
    const int NU = N * 64;

    const int R = (N + NB - 1) / NB;                    // nodes per bucket
    int cap = (3 * E / (2 * NB) + 256) & ~255;          // 1.5x mean, rounded
    if (cap < 512) cap = 512;

    // ws layout (uint units): xb[NU] | segs[NB*cap*2] | g_cnt[NB]
    //                         | spill_cnt[1] | align4 | spill[SPILL_CAP*4]
    size_t xb_off        = 0;
    size_t segs_off      = xb_off + (size_t)NU;
    size_t cnt_off       = segs_off + (size_t)NB * cap * 2;
    size_t spill_cnt_off = cnt_off + NB;
    size_t spill_off     = (spill_cnt_off + 1 + 3) & ~(size_t)3;
    size_t need          = (spill_off + (size_t)SPILL_CAP * 4) * 4;

    if (ws_size >= need && N >= 1 && N <= 16384 && R <= R_MAX && E > 0) {
        unsigned* xb        = (unsigned*)d_ws + xb_off;
        uint2*    segs      = (uint2*)((unsigned*)d_ws + segs_off);
        int*      g_cnt     = (int*)d_ws + cnt_off;
        int*      spill_cnt = (int*)d_ws + spill_cnt_off;
        int4*     spill     = (int4*)((unsigned*)d_ws + spill_off);

        const unsigned M = (unsigned)((0x100000000ULL + R - 1) / (unsigned)R);

        int conv_elems = (NU > NB + 1) ? NU : (NB + 1);
        int cgrid = (conv_elems + 255) / 256;
        int sgrid = (E + TILE - 1) / TILE;
        int agrid = (N + R - 1) / R;

        convert_kernel<<<cgrid, 256, 0, stream>>>(x, W, xb, g_cnt, spill_cnt, NU);
        sort_kernel<<<sgrid, 256, 0, stream>>>(src, dst, ew, g_cnt, spill_cnt,
                                               spill, segs, E, M, R, cap);
        acc_kernel<<<agrid, 512, 0, stream>>>(xb, g_cnt, spill_cnt, spill,
                                              segs, out, N, R, cap);
    } else {
        hipMemsetAsync(out, 0, (size_t)out_size * sizeof(float), stream);
        long long tt = (long long)E * 32;
        int grid = (int)((tt + 255) / 256);
        fallback_scatter<<<grid, 256, 0, stream>>>(x, W, ew, src, dst, out, E);
    }
}

// Round 7
// 54.946 us; speedup vs baseline: 8.4313x; 8.4313x over previous
//
#include <hip/hip_runtime.h>

// GraphConvolutionDiagLayer: out[dst[e]] += ew[e] * (x[src[e]] * W)
// N=10000, E=640000, F=128, fp32.
//
// Round 7: two-pass counting sort to per-NODE order + register accumulate.
//  Round-6 post-mortem: tile-sort (sort1) was fast (~10us) but the bucket
//  accumulator died on LDS fp32 atomics at 1 block/CU (441us, VALUBusy 2.4%
//  = pure latency serialization). Fix: second counting-sort pass to full
//  per-node segments (LDS *int* hist/cursors only), then the round-4-style
//  register gather over dense sorted records. No fp atomics anywhere.
//   K1 convert: xb[n*64+j] = pack2(bf16(x[n,j]*W[j]), bf16(x[n,j+64]*W[j+64]))
//               (2.56MB, L2-resident); zeroes g_cnt/spill_cnt.
//   K2 sort1:   2048-edge tiles -> NB=256 dst-range buckets (LDS hist+scan+
//               reorder, 1 global atomic per tile*bucket, coalesced stores).
//               Record: lo = src(14) | dl(7)<<14 | b<<21, hi = fp32 w.
//   K3 sort2:   per bucket: LDS int hist over R=40 nodes + scan + cursor
//               placement -> node-sorted records (src, w) + noff[n]=(start,cnt).
//   K4 gather2: one wave per node, unroll x8, register acc, dense write.
//  Spill list keeps correctness independent of cap; fallback if ws/N bad.

#define F_DIM 128
#define NB 256
#define TILE 2048
#define SPILL_CAP 8192
#define R_MAX 64

__device__ __forceinline__ unsigned f2bf_bits(float f)
{
    unsigned u = __float_as_uint(f);
    return (u + 0x7FFFu + ((u >> 16) & 1u)) >> 16;   // RNE to bf16
}

__global__ void __launch_bounds__(256)
convert_kernel(const float* __restrict__ x, const float* __restrict__ W,
               unsigned* __restrict__ xb, int* __restrict__ g_cnt,
               int* __restrict__ spill_cnt, int NU)
{
    int t = blockIdx.x * 256 + threadIdx.x;
    if (t < NU) {
        int n = t >> 6, j = t & 63;
        float v0 = x[n * F_DIM + j]      * W[j];
        float v1 = x[n * F_DIM + j + 64] * W[j + 64];
        xb[t] = f2bf_bits(v0) | (f2bf_bits(v1) << 16);
    }
    if (t < NB) g_cnt[t] = 0;
    if (t == NB) *spill_cnt = 0;
}

__global__ void __launch_bounds__(256)
sort1_kernel(const int* __restrict__ src, const int* __restrict__ dst,
             const float* __restrict__ ew,
             int* __restrict__ g_cnt, int* __restrict__ spill_cnt,
             int4* __restrict__ spill, uint2* __restrict__ segs,
             int E, unsigned M, int R, int cap)
{
    __shared__ unsigned reo_lo[TILE];
    __shared__ unsigned reo_hi[TILE];
    __shared__ int hist[NB], scn[NB], gbase[NB];

    int tid = threadIdx.x;
    int tile0 = blockIdx.x * TILE;
    int tcnt = E - tile0; if (tcnt > TILE) tcnt = TILE;

    if (tid < NB) hist[tid] = 0;
    __syncthreads();

    int b_k[8], rank_k[8]; unsigned lo_k[8], w_k[8];
    int kmax = 0;
    #pragma unroll
    for (int k = 0; k < 8; ++k) {
        int e = tile0 + k * 256 + tid;
        if (e < E) {
            int d = dst[e];
            int b = (int)__umulhi((unsigned)d, M);     // d / R (exact)
            int dl = d - b * R;
            b_k[kmax]    = b;
            lo_k[kmax]   = ((unsigned)src[e] & 0x3FFFu) | ((unsigned)dl << 14)
                         | ((unsigned)b << 21);
            w_k[kmax]    = __float_as_uint(ew[e]);
            rank_k[kmax] = atomicAdd(&hist[b], 1);     // LDS int atomic
            ++kmax;
        }
    }
    __syncthreads();

    if (tid < NB) scn[tid] = hist[tid];
    __syncthreads();
    for (int d = 1; d < NB; d <<= 1) {
        int v = 0;
        if (tid < NB && tid >= d) v = scn[tid - d];
        __syncthreads();
        if (tid < NB) scn[tid] += v;                    // inclusive scan
        __syncthreads();
    }

    for (int k = 0; k < kmax; ++k) {
        int b = b_k[k];
        int pos = (scn[b] - hist[b]) + rank_k[k];       // excl offset + rank
        reo_lo[pos] = lo_k[k];
        reo_hi[pos] = w_k[k];
    }
    if (tid < NB)
        gbase[tid] = hist[tid] ? atomicAdd(&g_cnt[tid], hist[tid]) : 0;
    __syncthreads();

    for (int p = tid; p < tcnt; p += 256) {
        unsigned lo = reo_lo[p];
        int b = (int)(lo >> 21);
        int slot = gbase[b] + (p - (scn[b] - hist[b]));
        if (slot < cap) {
            segs[(size_t)b * cap + slot] = make_uint2(lo, reo_hi[p]);
        } else {
            int sp = atomicAdd(spill_cnt, 1);
            if (sp < SPILL_CAP) {
                int dl = (int)((lo >> 14) & 0x7Fu);
                spill[sp] = make_int4(b * R + dl, (int)(lo & 0x3FFFu),
                                      (int)reo_hi[p], 0);
            }
        }
    }
}

// Per bucket: counting sort to node granularity. LDS int atomics only.
__global__ void __launch_bounds__(256)
sort2_kernel(const uint2* __restrict__ segs, const int* __restrict__ g_cnt,
             uint2* __restrict__ sorted2, uint2* __restrict__ noff,
             int N, int R, int cap)
{
    __shared__ int hist2[R_MAX], excl[R_MAX], cur[R_MAX];
    int b = blockIdx.x;
    int tid = threadIdx.x;
    int rows = N - b * R; if (rows > R) rows = R;
    if (rows <= 0) return;
    int cnt = g_cnt[b]; if (cnt > cap) cnt = cap;

    if (tid < rows) hist2[tid] = 0;
    __syncthreads();

    const uint2* seg = segs + (size_t)b * cap;
    for (int r = tid; r < cnt; r += 256)
        atomicAdd(&hist2[(seg[r].x >> 14) & 0x7Fu], 1);
    __syncthreads();

    if (tid == 0) {
        int s = 0;
        for (int i = 0; i < rows; ++i) { excl[i] = s; s += hist2[i]; }
    }
    __syncthreads();

    if (tid < rows) {
        cur[tid] = excl[tid];
        noff[b * R + tid] = make_uint2((unsigned)(b * cap + excl[tid]),
                                       (unsigned)hist2[tid]);
    }
    __syncthreads();

    uint2* so = sorted2 + (size_t)b * cap;
    for (int r = tid; r < cnt; r += 256) {
        uint2 q = seg[r];
        int dl = (int)((q.x >> 14) & 0x7Fu);
        int pos = atomicAdd(&cur[dl], 1);
        so[pos] = make_uint2(q.x & 0x3FFFu, q.y);
    }
}

__global__ void __launch_bounds__(256)
gather2_kernel(const unsigned* __restrict__ xb, const uint2* __restrict__ noff,
               const uint2* __restrict__ sorted2,
               const int* __restrict__ spill_cnt, const int4* __restrict__ spill,
               float* __restrict__ out, int N)
{
    int wid  = threadIdx.x >> 6;
    int lane = threadIdx.x & 63;
    int n = blockIdx.x * 4 + wid;
    if (n >= N) return;

    uint2 nf = noff[n];
    const uint2* p = sorted2 + nf.x;
    int c = (int)nf.y;

    float ax = 0.f, ay = 0.f;
    int i = 0;
    for (; i + 8 <= c; i += 8) {
        unsigned rs[8]; float wv[8];
        #pragma unroll
        for (int k = 0; k < 8; ++k) {
            uint2 q = p[i + k];
            rs[k] = q.x; wv[k] = __uint_as_float(q.y);
        }
        unsigned rv[8];
        #pragma unroll
        for (int k = 0; k < 8; ++k)
            rv[k] = xb[(size_t)rs[k] * 64 + lane];
        #pragma unroll
        for (int k = 0; k < 8; ++k) {
            ax += wv[k] * __uint_as_float(rv[k] << 16);
            ay += wv[k] * __uint_as_float(rv[k] & 0xFFFF0000u);
        }
    }
    for (; i < c; ++i) {
        uint2 q = p[i];
        unsigned rv = xb[(size_t)q.x * 64 + lane];
        float w = __uint_as_float(q.y);
        ax += w * __uint_as_float(rv << 16);
        ay += w * __uint_as_float(rv & 0xFFFF0000u);
    }

    // spill fold-in (normally empty: one broadcast load + skip)
    int sc = *spill_cnt; if (sc > SPILL_CAP) sc = SPILL_CAP;
    for (int t = 0; t < sc; ++t) {
        int4 sp = spill[t];
        if (sp.x == n) {
            unsigned rv = xb[(size_t)sp.y * 64 + lane];
            float w = __int_as_float(sp.z);
            ax += w * __uint_as_float(rv << 16);
            ay += w * __uint_as_float(rv & 0xFFFF0000u);
        }
    }

    out[(size_t)n * F_DIM + lane]      = ax;
    out[(size_t)n * F_DIM + 64 + lane] = ay;
}

// ---- fallback: direct fp32 atomic scatter ----
__global__ void __launch_bounds__(256)
fallback_scatter(const float* __restrict__ x, const float* __restrict__ W,
                 const float* __restrict__ ew, const int* __restrict__ src,
                 const int* __restrict__ dst, float* __restrict__ out, int E)
{
    int t = blockIdx.x * 256 + threadIdx.x;
    int e = t >> 5;
    if (e >= E) return;
    int f4 = t & 31;
    int   s = src[e];
    int   d = dst[e];
    float w = ew[e];
    float4 xv = reinterpret_cast<const float4*>(x)[s * 32 + f4];
    float4 wv = reinterpret_cast<const float4*>(W)[f4];
    float* o = out + d * F_DIM + f4 * 4;
    unsafeAtomicAdd(o + 0, xv.x * wv.x * w);
    unsafeAtomicAdd(o + 1, xv.y * wv.y * w);
    unsafeAtomicAdd(o + 2, xv.z * wv.z * w);
    unsafeAtomicAdd(o + 3, xv.w * wv.w * w);
}

extern "C" void kernel_launch(void* const* d_in, const int* in_sizes, int n_in,
                              void* d_out, int out_size, void* d_ws, size_t ws_size,
                              hipStream_t stream)
{
    const float* x   = (const float*)d_in[0];
    const float* W   = (const float*)d_in[1];
    const float* ew  = (const float*)d_in[2];
    const int*   src = (const int*)d_in[3];
    const int*   dst = (const int*)d_in[4];
    float*       out = (float*)d_out;

    const int E  = in_sizes[2];
    const int N  = out_size / F_DIM;
    const int NU = N * 64;

    const int R = (N + NB - 1) / NB;                    // nodes per bucket
    int cap = (3 * E / (2 * NB) + 256) & ~255;          // 1.5x mean, rounded
    if (cap < 512) cap = 512;

    // ws layout (uint units): xb[NU] | segs[NB*cap*2] | sorted2[NB*cap*2]
    //   | g_cnt[NB] | spill_cnt[1] | align4 | spill[SPILL_CAP*4] | noff[2N]
    size_t xb_off        = 0;
    size_t segs_off      = xb_off + (size_t)NU;
    size_t sorted2_off   = segs_off + (size_t)NB * cap * 2;
    size_t cnt_off       = sorted2_off + (size_t)NB * cap * 2;
    size_t spill_cnt_off = cnt_off + NB;
    size_t spill_off     = (spill_cnt_off + 1 + 3) & ~(size_t)3;
    size_t noff_off      = spill_off + (size_t)SPILL_CAP * 4;
    size_t need          = (noff_off + (size_t)2 * N) * 4;

    if (ws_size >= need && N >= 1 && N <= 16384 && R <= R_MAX && E > 0) {
        unsigned* xb        = (unsigned*)d_ws + xb_off;
        uint2*    segs      = (uint2*)((unsigned*)d_ws + segs_off);
        uint2*    sorted2   = (uint2*)((unsigned*)d_ws + sorted2_off);
        int*      g_cnt     = (int*)d_ws + cnt_off;
        int*      spill_cnt = (int*)d_ws + spill_cnt_off;
        int4*     spill     = (int4*)((unsigned*)d_ws + spill_off);
        uint2*    noff      = (uint2*)((unsigned*)d_ws + noff_off);

        const unsigned M = (unsigned)((0x100000000ULL + R - 1) / (unsigned)R);

        int conv_elems = (NU > NB + 1) ? NU : (NB + 1);
        int cgrid  = (conv_elems + 255) / 256;
        int s1grid = (E + TILE - 1) / TILE;
        int s2grid = (N + R - 1) / R;
        int ggrid  = (N + 3) / 4;

        convert_kernel<<<cgrid, 256, 0, stream>>>(x, W, xb, g_cnt, spill_cnt, NU);
        sort1_kernel<<<s1grid, 256, 0, stream>>>(src, dst, ew, g_cnt, spill_cnt,
                                                 spill, segs, E, M, R, cap);
        sort2_kernel<<<s2grid, 256, 0, stream>>>(segs, g_cnt, sorted2, noff,
                                                 N, R, cap);
        gather2_kernel<<<ggrid, 256, 0, stream>>>(xb, noff, sorted2, spill_cnt,
                                                  spill, out, N);
    } else {
        hipMemsetAsync(out, 0, (size_t)out_size * sizeof(float), stream);
        long long tt = (long long)E * 32;
        int grid = (int)((tt + 255) / 256);
        if (grid < 1) grid = 1;
        fallback_scatter<<<grid, 256, 0, stream>>>(x, W, ew, src, dst, out, E);
    }
}

// Round 8
// 51.861 us; speedup vs baseline: 8.9327x; 1.0595x over previous
//
#include <hip/hip_runtime.h>

// GraphConvolutionDiagLayer: out[dst[e]] += ew[e] * (x[src[e]] * W)
// N=10000, E=640000, F=128, fp32.
//
// Round 8 (from round-7's 54.9us; gather2 ~25us dominant):
//   K1 convert: xb[n*64+j] = pack2(bf16(x[n,j]*W[j]), bf16(x[n,j+64]*W[j+64]))
//               (2.56MB, L2-resident); zeroes g_cnt/spill_cnt.
//   K2 sort1:   2048-edge tiles -> NB=256 dst-range buckets (LDS hist+scan+
//               reorder, 1 global atomic per tile*bucket, coalesced stores).
//               NOW with fully static per-thread register indexing (rule #20:
//               runtime-indexed VGPR arrays go to scratch).
//   K3 sort2:   per bucket -> per-NODE segments, SoA output: u16 srcs +
//               f32 ws, segment starts padded to 8 records (aligned uint4/
//               float4 gather loads). Padded total <= cap+8*R <= cap2: no
//               overflow possible.
//   K4 gather2: one wave per node, 16-record batches: 2xuint4 + 4xfloat4 +
//               16 row loads (22 VMEM/16 recs, 16 rows in flight), register
//               acc, dense write.
//  Spill list keeps correctness independent of cap; fallback if ws/N bad.

#define F_DIM 128
#define NB 256
#define TILE 2048
#define SPILL_CAP 8192
#define R_MAX 64

__device__ __forceinline__ unsigned f2bf_bits(float f)
{
    unsigned u = __float_as_uint(f);
    return (u + 0x7FFFu + ((u >> 16) & 1u)) >> 16;   // RNE to bf16
}

__global__ void __launch_bounds__(256)
convert_kernel(const float* __restrict__ x, const float* __restrict__ W,
               unsigned* __restrict__ xb, int* __restrict__ g_cnt,
               int* __restrict__ spill_cnt, int NU)
{
    int t = blockIdx.x * 256 + threadIdx.x;
    if (t < NU) {
        int n = t >> 6, j = t & 63;
        float v0 = x[n * F_DIM + j]      * W[j];
        float v1 = x[n * F_DIM + j + 64] * W[j + 64];
        xb[t] = f2bf_bits(v0) | (f2bf_bits(v1) << 16);
    }
    if (t < NB) g_cnt[t] = 0;
    if (t == NB) *spill_cnt = 0;
}

__global__ void __launch_bounds__(256)
sort1_kernel(const int* __restrict__ src, const int* __restrict__ dst,
             const float* __restrict__ ew,
             int* __restrict__ g_cnt, int* __restrict__ spill_cnt,
             int4* __restrict__ spill, uint2* __restrict__ segs,
             int E, unsigned M, int R, int cap)
{
    __shared__ unsigned reo_lo[TILE];
    __shared__ unsigned reo_hi[TILE];
    __shared__ int hist[NB], scn[NB], gbase[NB];

    int tid = threadIdx.x;
    int tile0 = blockIdx.x * TILE;
    int tcnt = E - tile0; if (tcnt > TILE) tcnt = TILE;

    if (tid < NB) hist[tid] = 0;
    __syncthreads();

    int b_k[8], rank_k[8]; unsigned lo_k[8], w_k[8];
    #pragma unroll
    for (int k = 0; k < 8; ++k) {
        int e = tile0 + k * 256 + tid;
        b_k[k] = -1; rank_k[k] = 0; lo_k[k] = 0; w_k[k] = 0;
        if (e < E) {
            int d = dst[e];
            int b = (int)__umulhi((unsigned)d, M);     // d / R (exact)
            int dl = d - b * R;
            b_k[k]    = b;
            lo_k[k]   = ((unsigned)src[e] & 0x3FFFu) | ((unsigned)dl << 14)
                      | ((unsigned)b << 21);
            w_k[k]    = __float_as_uint(ew[e]);
            rank_k[k] = atomicAdd(&hist[b], 1);        // LDS int atomic
        }
    }
    __syncthreads();

    if (tid < NB) scn[tid] = hist[tid];
    __syncthreads();
    for (int d = 1; d < NB; d <<= 1) {
        int v = 0;
        if (tid < NB && tid >= d) v = scn[tid - d];
        __syncthreads();
        if (tid < NB) scn[tid] += v;                    // inclusive scan
        __syncthreads();
    }

    #pragma unroll
    for (int k = 0; k < 8; ++k) {
        if (b_k[k] >= 0) {
            int b = b_k[k];
            int pos = (scn[b] - hist[b]) + rank_k[k];   // excl offset + rank
            reo_lo[pos] = lo_k[k];
            reo_hi[pos] = w_k[k];
        }
    }
    if (tid < NB)
        gbase[tid] = hist[tid] ? atomicAdd(&g_cnt[tid], hist[tid]) : 0;
    __syncthreads();

    for (int p = tid; p < tcnt; p += 256) {
        unsigned lo = reo_lo[p];
        int b = (int)(lo >> 21);
        int slot = gbase[b] + (p - (scn[b] - hist[b]));
        if (slot < cap) {
            segs[(size_t)b * cap + slot] = make_uint2(lo, reo_hi[p]);
        } else {
            int sp = atomicAdd(spill_cnt, 1);
            if (sp < SPILL_CAP) {
                int dl = (int)((lo >> 14) & 0x7Fu);
                spill[sp] = make_int4(b * R + dl, (int)(lo & 0x3FFFu),
                                      (int)reo_hi[p], 0);
            }
        }
    }
}

// Per bucket: counting sort to node granularity, SoA output with 8-record
// aligned segment starts. LDS int atomics only.
__global__ void __launch_bounds__(256)
sort2_kernel(const uint2* __restrict__ segs, const int* __restrict__ g_cnt,
             unsigned short* __restrict__ s2src, float* __restrict__ s2w,
             uint2* __restrict__ noff, int N, int R, int cap, int cap2)
{
    __shared__ int hist2[R_MAX], pexcl[R_MAX], cur[R_MAX];
    int b = blockIdx.x;
    int tid = threadIdx.x;
    int rows = N - b * R; if (rows > R) rows = R;
    if (rows <= 0) return;
    int cnt = g_cnt[b]; if (cnt > cap) cnt = cap;

    if (tid < rows) hist2[tid] = 0;
    __syncthreads();

    const uint2* seg = segs + (size_t)b * cap;
    for (int r = tid; r < cnt; r += 256)
        atomicAdd(&hist2[(seg[r].x >> 14) & 0x7Fu], 1);
    __syncthreads();

    if (tid == 0) {
        int s = 0;
        for (int i = 0; i < rows; ++i) {
            pexcl[i] = s;
            s += (hist2[i] + 7) & ~7;        // pad each segment to x8 records
        }
    }
    __syncthreads();

    if (tid < rows) {
        cur[tid] = pexcl[tid];
        noff[b * R + tid] = make_uint2((unsigned)(b * cap2 + pexcl[tid]),
                                       (unsigned)hist2[tid]);
    }
    __syncthreads();

    unsigned short* so = s2src + (size_t)b * cap2;
    float*          wo = s2w   + (size_t)b * cap2;
    for (int r = tid; r < cnt; r += 256) {
        uint2 q = seg[r];
        int dl = (int)((q.x >> 14) & 0x7Fu);
        int pos = atomicAdd(&cur[dl], 1);
        so[pos] = (unsigned short)(q.x & 0x3FFFu);
        wo[pos] = __uint_as_float(q.y);
    }
}

__global__ void __launch_bounds__(512)
gather2_kernel(const unsigned* __restrict__ xb, const uint2* __restrict__ noff,
               const unsigned short* __restrict__ s2src,
               const float* __restrict__ s2w,
               const int* __restrict__ spill_cnt, const int4* __restrict__ spill,
               float* __restrict__ out, int N)
{
    int wid  = threadIdx.x >> 6;
    int lane = threadIdx.x & 63;
    int n = blockIdx.x * 8 + wid;
    if (n >= N) return;

    uint2 nf = noff[n];
    const unsigned short* ps = s2src + nf.x;
    const float*          pw = s2w   + nf.x;
    int c = (int)nf.y;

    float ax = 0.f, ay = 0.f;
    int i = 0;
    for (; i + 16 <= c; i += 16) {
        uint4 sa = *(const uint4*)(ps + i);
        uint4 sb = *(const uint4*)(ps + i + 8);
        float4 wa = *(const float4*)(pw + i);
        float4 wb = *(const float4*)(pw + i + 4);
        float4 wc = *(const float4*)(pw + i + 8);
        float4 wd = *(const float4*)(pw + i + 12);
        unsigned sv[16] = {sa.x & 0xFFFFu, sa.x >> 16, sa.y & 0xFFFFu, sa.y >> 16,
                           sa.z & 0xFFFFu, sa.z >> 16, sa.w & 0xFFFFu, sa.w >> 16,
                           sb.x & 0xFFFFu, sb.x >> 16, sb.y & 0xFFFFu, sb.y >> 16,
                           sb.z & 0xFFFFu, sb.z >> 16, sb.w & 0xFFFFu, sb.w >> 16};
        float wv[16] = {wa.x, wa.y, wa.z, wa.w, wb.x, wb.y, wb.z, wb.w,
                        wc.x, wc.y, wc.z, wc.w, wd.x, wd.y, wd.z, wd.w};
        unsigned rv[16];
        #pragma unroll
        for (int k = 0; k < 16; ++k)
            rv[k] = xb[(size_t)sv[k] * 64 + lane];
        #pragma unroll
        for (int k = 0; k < 16; ++k) {
            ax += wv[k] * __uint_as_float(rv[k] << 16);
            ay += wv[k] * __uint_as_float(rv[k] & 0xFFFF0000u);
        }
    }
    for (; i + 8 <= c; i += 8) {
        uint4 sa = *(const uint4*)(ps + i);
        float4 wa = *(const float4*)(pw + i);
        float4 wb = *(const float4*)(pw + i + 4);
        unsigned sv[8] = {sa.x & 0xFFFFu, sa.x >> 16, sa.y & 0xFFFFu, sa.y >> 16,
                          sa.z & 0xFFFFu, sa.z >> 16, sa.w & 0xFFFFu, sa.w >> 16};
        float wv[8] = {wa.x, wa.y, wa.z, wa.w, wb.x, wb.y, wb.z, wb.w};
        unsigned rv[8];
        #pragma unroll
        for (int k = 0; k < 8; ++k)
            rv[k] = xb[(size_t)sv[k] * 64 + lane];
        #pragma unroll
        for (int k = 0; k < 8; ++k) {
            ax += wv[k] * __uint_as_float(rv[k] << 16);
            ay += wv[k] * __uint_as_float(rv[k] & 0xFFFF0000u);
        }
    }
    for (; i < c; ++i) {
        unsigned s = ps[i];
        float w = pw[i];
        unsigned rv = xb[(size_t)s * 64 + lane];
        ax += w * __uint_as_float(rv << 16);
        ay += w * __uint_as_float(rv & 0xFFFF0000u);
    }

    // spill fold-in (normally empty: one broadcast load + skip)
    int sc = *spill_cnt; if (sc > SPILL_CAP) sc = SPILL_CAP;
    for (int t = 0; t < sc; ++t) {
        int4 sp = spill[t];
        if (sp.x == n) {
            unsigned rv = xb[(size_t)sp.y * 64 + lane];
            float w = __int_as_float(sp.z);
            ax += w * __uint_as_float(rv << 16);
            ay += w * __uint_as_float(rv & 0xFFFF0000u);
        }
    }

    out[(size_t)n * F_DIM + lane]      = ax;
    out[(size_t)n * F_DIM + 64 + lane] = ay;
}

// ---- fallback: direct fp32 atomic scatter ----
__global__ void __launch_bounds__(256)
fallback_scatter(const float* __restrict__ x, const float* __restrict__ W,
                 const float* __restrict__ ew, const int* __restrict__ src,
                 const int* __restrict__ dst, float* __restrict__ out, int E)
{
    int t = blockIdx.x * 256 + threadIdx.x;
    int e = t >> 5;
    if (e >= E) return;
    int f4 = t & 31;
    int   s = src[e];
    int   d = dst[e];
    float w = ew[e];
    float4 xv = reinterpret_cast<const float4*>(x)[s * 32 + f4];
    float4 wv = reinterpret_cast<const float4*>(W)[f4];
    float* o = out + d * F_DIM + f4 * 4;
    unsafeAtomicAdd(o + 0, xv.x * wv.x * w);
    unsafeAtomicAdd(o + 1, xv.y * wv.y * w);
    unsafeAtomicAdd(o + 2, xv.z * wv.z * w);
    unsafeAtomicAdd(o + 3, xv.w * wv.w * w);
}

extern "C" void kernel_launch(void* const* d_in, const int* in_sizes, int n_in,
                              void* d_out, int out_size, void* d_ws, size_t ws_size,
                              hipStream_t stream)
{
    const float* x   = (const float*)d_in[0];
    const float* W   = (const float*)d_in[1];
    const float* ew  = (const float*)d_in[2];
    const int*   src = (const int*)d_in[3];
    const int*   dst = (const int*)d_in[4];
    float*       out = (float*)d_out;

    const int E  = in_sizes[2];
    const int N  = out_size / F_DIM;
    const int NU = N * 64;

    const int R = (N + NB - 1) / NB;                    // nodes per bucket
    int cap = (3 * E / (2 * NB) + 256) & ~255;          // 1.5x mean, rounded
    if (cap < 512) cap = 512;
    const int cap2 = cap + 8 * R_MAX;                   // padded-output cap

    // ws layout (uint units): xb[NU] | segs[NB*cap*2] | s2src[NB*cap2/2]
    //   | s2w[NB*cap2] | g_cnt[NB] | spill_cnt[1] | align4
    //   | spill[SPILL_CAP*4] | noff[2N]
    size_t xb_off        = 0;
    size_t segs_off      = xb_off + (size_t)NU;
    size_t s2src_off     = segs_off + (size_t)NB * cap * 2;
    size_t s2w_off       = s2src_off + (size_t)NB * cap2 / 2;
    size_t cnt_off       = s2w_off + (size_t)NB * cap2;
    size_t spill_cnt_off = cnt_off + NB;
    size_t spill_off     = (spill_cnt_off + 1 + 3) & ~(size_t)3;
    size_t noff_off      = spill_off + (size_t)SPILL_CAP * 4;
    size_t need          = (noff_off + (size_t)2 * N) * 4;

    if (ws_size >= need && N >= 1 && N <= 16384 && R <= R_MAX && E > 0) {
        unsigned*       xb        = (unsigned*)d_ws + xb_off;
        uint2*          segs      = (uint2*)((unsigned*)d_ws + segs_off);
        unsigned short* s2src     = (unsigned short*)((unsigned*)d_ws + s2src_off);
        float*          s2w       = (float*)((unsigned*)d_ws + s2w_off);
        int*            g_cnt     = (int*)d_ws + cnt_off;
        int*            spill_cnt = (int*)d_ws + spill_cnt_off;
        int4*           spill     = (int4*)((unsigned*)d_ws + spill_off);
        uint2*          noff      = (uint2*)((unsigned*)d_ws + noff_off);

        const unsigned M = (unsigned)((0x100000000ULL + R - 1) / (unsigned)R);

        int conv_elems = (NU > NB + 1) ? NU : (NB + 1);
        int cgrid  = (conv_elems + 255) / 256;
        int s1grid = (E + TILE - 1) / TILE;
        int s2grid = (N + R - 1) / R;
        int ggrid  = (N + 7) / 8;

        convert_kernel<<<cgrid, 256, 0, stream>>>(x, W, xb, g_cnt, spill_cnt, NU);
        sort1_kernel<<<s1grid, 256, 0, stream>>>(src, dst, ew, g_cnt, spill_cnt,
                                                 spill, segs, E, M, R, cap);
        sort2_kernel<<<s2grid, 256, 0, stream>>>(segs, g_cnt, s2src, s2w, noff,
                                                 N, R, cap, cap2);
        gather2_kernel<<<ggrid, 512, 0, stream>>>(xb, noff, s2src, s2w, spill_cnt,
                                                  spill, out, N);
    } else {
        hipMemsetAsync(out, 0, (size_t)out_size * sizeof(float), stream);
        long long tt = (long long)E * 32;
        int grid = (int)((tt + 255) / 256);
        if (grid < 1) grid = 1;
        fallback_scatter<<<grid, 256, 0, stream>>>(x, W, ew, src, dst, out, E);
    }
}

// Round 9
// 46.438 us; speedup vs baseline: 9.9759x; 1.1168x over previous
//
#include <hip/hip_runtime.h>

// GraphConvolutionDiagLayer: out[dst[e]] += ew[e] * (x[src[e]] * W)
// N=10000, E=640000, F=128, fp32.
//
// Round 9: 3 dispatches.
//   D1 memset:      zero g_cnt[NB]+spill_cnt (1KB).
//   D2 conv_sort1:  blocks [0,cgrid) convert xb = pack2(bf16(x*W)) via uint4;
//                   blocks [cgrid,..) = sort1: 2048-edge tiles -> NB=256
//                   dst-range buckets (LDS hist + WAVE-SHUFFLE scan (2
//                   barriers, was 16) + reorder, 1 global atomic per
//                   tile*bucket, coalesced 8B record stores).
//   D3 bucket:      one block per bucket; seg records -> registers (8/thr),
//                   LDS int hist -> shuffle scan -> LDS SoA placement
//                   (u16 src + f32 w, segments padded to x8), then 8 waves
//                   gather 40 nodes: records broadcast from LDS, xb rows
//                   from L2, register acc, dense single write.
//                   (kills sort2's global write + gather's record re-read)
//  Spill list keeps correctness independent of cap; fallback if ws/N bad.

#define F_DIM 128
#define NB 256
#define TILE 2048
#define SPILL_CAP 8192
#define R_MAX 64

__device__ __forceinline__ unsigned f2bf_bits(float f)
{
    unsigned u = __float_as_uint(f);
    return (u + 0x7FFFu + ((u >> 16) & 1u)) >> 16;   // RNE to bf16
}

__global__ void __launch_bounds__(256)
conv_sort1_kernel(const float* __restrict__ x, const float* __restrict__ W,
                  unsigned* __restrict__ xb,
                  const int* __restrict__ src, const int* __restrict__ dst,
                  const float* __restrict__ ew,
                  int* __restrict__ g_cnt, int* __restrict__ spill_cnt,
                  int4* __restrict__ spill, uint2* __restrict__ segs,
                  int NU4, int cgrid, int E, unsigned M, int R, int cap)
{
    __shared__ unsigned reo_lo[TILE];
    __shared__ unsigned reo_hi[TILE];
    __shared__ int hist[NB], scn[NB], gbase[NB], wsum[4];

    int tid = threadIdx.x;

    if ((int)blockIdx.x < cgrid) {
        // ---------------- convert part ----------------
        int t = blockIdx.x * 256 + tid;
        if (t < NU4) {
            int n = t >> 4, jq = t & 15;
            const float4* xr = (const float4*)(x + (size_t)n * F_DIM + jq * 4);
            float4 a  = xr[0];
            float4 bb = xr[16];                 // +64 floats
            const float4* wr = (const float4*)(W + jq * 4);
            float4 wa = wr[0], wb = wr[16];
            uint4 o;
            o.x = f2bf_bits(a.x * wa.x) | (f2bf_bits(bb.x * wb.x) << 16);
            o.y = f2bf_bits(a.y * wa.y) | (f2bf_bits(bb.y * wb.y) << 16);
            o.z = f2bf_bits(a.z * wa.z) | (f2bf_bits(bb.z * wb.z) << 16);
            o.w = f2bf_bits(a.w * wa.w) | (f2bf_bits(bb.w * wb.w) << 16);
            *(uint4*)(xb + (size_t)n * 64 + jq * 4) = o;
        }
        return;
    }

    // ---------------- sort1 part ----------------
    int tile0 = ((int)blockIdx.x - cgrid) * TILE;
    int tcnt = E - tile0; if (tcnt > TILE) tcnt = TILE;

    if (tid < NB) hist[tid] = 0;
    __syncthreads();

    int b_k[8], rank_k[8]; unsigned lo_k[8], w_k[8];
    #pragma unroll
    for (int k = 0; k < 8; ++k) {
        int e = tile0 + k * 256 + tid;
        b_k[k] = -1; rank_k[k] = 0; lo_k[k] = 0; w_k[k] = 0;
        if (e < E) {
            int d = dst[e];
            int b = (int)__umulhi((unsigned)d, M);     // d / R (exact)
            int dl = d - b * R;
            b_k[k]    = b;
            lo_k[k]   = ((unsigned)src[e] & 0x3FFFu) | ((unsigned)dl << 14)
                      | ((unsigned)b << 21);
            w_k[k]    = __float_as_uint(ew[e]);
            rank_k[k] = atomicAdd(&hist[b], 1);        // LDS int atomic
        }
    }
    __syncthreads();

    // wave-shuffle inclusive scan over NB=256 (4 waves, 2 barriers)
    {
        int lane6 = tid & 63, wv = tid >> 6;
        int v = hist[tid];
        #pragma unroll
        for (int d = 1; d < 64; d <<= 1) {
            int t2 = __shfl_up(v, d);
            if (lane6 >= d) v += t2;
        }
        if (lane6 == 63) wsum[wv] = v;
        __syncthreads();
        int woff = 0;
        #pragma unroll
        for (int i2 = 0; i2 < 4; ++i2) if (i2 < wv) woff += wsum[i2];
        scn[tid] = v + woff;                            // inclusive scan
        __syncthreads();
    }

    #pragma unroll
    for (int k = 0; k < 8; ++k) {
        if (b_k[k] >= 0) {
            int b = b_k[k];
            int pos = (scn[b] - hist[b]) + rank_k[k];   // excl offset + rank
            reo_lo[pos] = lo_k[k];
            reo_hi[pos] = w_k[k];
        }
    }
    if (tid < NB)
        gbase[tid] = hist[tid] ? atomicAdd(&g_cnt[tid], hist[tid]) : 0;
    __syncthreads();

    for (int p = tid; p < tcnt; p += 256) {
        unsigned lo = reo_lo[p];
        int b = (int)(lo >> 21);
        int slot = gbase[b] + (p - (scn[b] - hist[b]));
        if (slot < cap) {
            segs[(size_t)b * cap + slot] = make_uint2(lo, reo_hi[p]);
        } else {
            int sp = atomicAdd(spill_cnt, 1);
            if (sp < SPILL_CAP) {
                int dl = (int)((lo >> 14) & 0x7Fu);
                spill[sp] = make_int4(b * R + dl, (int)(lo & 0x3FFFu),
                                      (int)reo_hi[p], 0);
            }
        }
    }
}

// One block per bucket: register-staged counting sort to node order in LDS,
// then 8-wave gather with register accumulation.
__global__ void __launch_bounds__(512)
bucket_kernel(const unsigned* __restrict__ xb, const uint2* __restrict__ segs,
              const int* __restrict__ g_cnt, const int* __restrict__ spill_cnt,
              const int4* __restrict__ spill, float* __restrict__ out,
              int N, int R, int cap, int cap2)
{
    extern __shared__ unsigned char smem[];
    float*          w_l = (float*)smem;                       // [cap2]
    unsigned short* s_l = (unsigned short*)(w_l + cap2);      // [cap2]
    __shared__ int hist2[R_MAX], pexcl[R_MAX], cur[R_MAX];

    int b   = blockIdx.x;
    int tid = threadIdx.x;
    int rows = N - b * R; if (rows > R) rows = R;
    if (rows <= 0) return;

    if (tid < R_MAX) hist2[tid] = 0;
    __syncthreads();

    int cnt = g_cnt[b]; if (cnt > cap) cnt = cap;
    const uint2* seg = segs + (size_t)b * cap;

    unsigned lo_r[8], hi_r[8];
    #pragma unroll
    for (int k = 0; k < 8; ++k) {
        int r = tid + k * 512;
        lo_r[k] = 0xFFFFFFFFu; hi_r[k] = 0;
        if (r < cnt) {
            uint2 q = seg[r];
            lo_r[k] = q.x; hi_r[k] = q.y;
            atomicAdd(&hist2[(q.x >> 14) & 0x7Fu], 1);
        }
    }
    __syncthreads();

    if (tid < 64) {
        int h = (tid < rows) ? hist2[tid] : 0;
        int p = (h + 7) & ~7;                 // pad segments to x8 records
        int v = p;
        #pragma unroll
        for (int d = 1; d < 64; d <<= 1) {
            int t2 = __shfl_up(v, d);
            if (tid >= d) v += t2;
        }
        int excl = v - p;
        if (tid < rows) { pexcl[tid] = excl; cur[tid] = excl; }
    }
    __syncthreads();

    #pragma unroll
    for (int k = 0; k < 8; ++k) {
        if (lo_r[k] != 0xFFFFFFFFu) {
            int dl = (int)((lo_r[k] >> 14) & 0x7Fu);
            int pos = atomicAdd(&cur[dl], 1);  // LDS int atomic
            s_l[pos] = (unsigned short)(lo_r[k] & 0x3FFFu);
            w_l[pos] = __uint_as_float(hi_r[k]);
        }
    }
    __syncthreads();

    // ---------------- gather phase ----------------
    int wid = tid >> 6, lane = tid & 63;
    int sc = *spill_cnt; if (sc > SPILL_CAP) sc = SPILL_CAP;

    for (int dl = wid; dl < rows; dl += 8) {
        int c    = hist2[dl];
        int base = pexcl[dl];
        const unsigned short* ps = s_l + base;
        const float*          pw = w_l + base;

        float ax = 0.f, ay = 0.f;
        int i = 0;
        for (; i + 16 <= c; i += 16) {
            uint4 sa = *(const uint4*)(ps + i);
            uint4 sb = *(const uint4*)(ps + i + 8);
            float4 wa = *(const float4*)(pw + i);
            float4 wb = *(const float4*)(pw + i + 4);
            float4 wc = *(const float4*)(pw + i + 8);
            float4 wd = *(const float4*)(pw + i + 12);
            unsigned sv[16] = {sa.x & 0xFFFFu, sa.x >> 16, sa.y & 0xFFFFu, sa.y >> 16,
                               sa.z & 0xFFFFu, sa.z >> 16, sa.w & 0xFFFFu, sa.w >> 16,
                               sb.x & 0xFFFFu, sb.x >> 16, sb.y & 0xFFFFu, sb.y >> 16,
                               sb.z & 0xFFFFu, sb.z >> 16, sb.w & 0xFFFFu, sb.w >> 16};
            float wv[16] = {wa.x, wa.y, wa.z, wa.w, wb.x, wb.y, wb.z, wb.w,
                            wc.x, wc.y, wc.z, wc.w, wd.x, wd.y, wd.z, wd.w};
            unsigned rv[16];
            #pragma unroll
            for (int k = 0; k < 16; ++k)
                rv[k] = xb[(size_t)sv[k] * 64 + lane];
            #pragma unroll
            for (int k = 0; k < 16; ++k) {
                ax += wv[k] * __uint_as_float(rv[k] << 16);
                ay += wv[k] * __uint_as_float(rv[k] & 0xFFFF0000u);
            }
        }
        for (; i + 8 <= c; i += 8) {
            uint4 sa = *(const uint4*)(ps + i);
            float4 wa = *(const float4*)(pw + i);
            float4 wb = *(const float4*)(pw + i + 4);
            unsigned sv[8] = {sa.x & 0xFFFFu, sa.x >> 16, sa.y & 0xFFFFu, sa.y >> 16,
                              sa.z & 0xFFFFu, sa.z >> 16, sa.w & 0xFFFFu, sa.w >> 16};
            float wv[8] = {wa.x, wa.y, wa.z, wa.w, wb.x, wb.y, wb.z, wb.w};
            unsigned rv[8];
            #pragma unroll
            for (int k = 0; k < 8; ++k)
                rv[k] = xb[(size_t)sv[k] * 64 + lane];
            #pragma unroll
            for (int k = 0; k < 8; ++k) {
                ax += wv[k] * __uint_as_float(rv[k] << 16);
                ay += wv[k] * __uint_as_float(rv[k] & 0xFFFF0000u);
            }
        }
        for (; i < c; ++i) {
            unsigned s = ps[i];
            float w = pw[i];
            unsigned rv = xb[(size_t)s * 64 + lane];
            ax += w * __uint_as_float(rv << 16);
            ay += w * __uint_as_float(rv & 0xFFFF0000u);
        }

        int n = b * R + dl;
        for (int t = 0; t < sc; ++t) {          // spill fold-in (normally 0)
            int4 sp = spill[t];
            if (sp.x == n) {
                unsigned rv = xb[(size_t)sp.y * 64 + lane];
                float w = __int_as_float(sp.z);
                ax += w * __uint_as_float(rv << 16);
                ay += w * __uint_as_float(rv & 0xFFFF0000u);
            }
        }

        out[(size_t)n * F_DIM + lane]      = ax;
        out[(size_t)n * F_DIM + 64 + lane] = ay;
    }
}

// ---- fallback: direct fp32 atomic scatter ----
__global__ void __launch_bounds__(256)
fallback_scatter(const float* __restrict__ x, const float* __restrict__ W,
                 const float* __restrict__ ew, const int* __restrict__ src,
                 const int* __restrict__ dst, float* __restrict__ out, int E)
{
    int t = blockIdx.x * 256 + threadIdx.x;
    int e = t >> 5;
    if (e >= E) return;
    int f4 = t & 31;
    int   s = src[e];
    int   d = dst[e];
    float w = ew[e];
    float4 xv = reinterpret_cast<const float4*>(x)[s * 32 + f4];
    float4 wv = reinterpret_cast<const float4*>(W)[f4];
    float* o = out + d * F_DIM + f4 * 4;
    unsafeAtomicAdd(o + 0, xv.x * wv.x * w);
    unsafeAtomicAdd(o + 1, xv.y * wv.y * w);
    unsafeAtomicAdd(o + 2, xv.z * wv.z * w);
    unsafeAtomicAdd(o + 3, xv.w * wv.w * w);
}

extern "C" void kernel_launch(void* const* d_in, const int* in_sizes, int n_in,
                              void* d_out, int out_size, void* d_ws, size_t ws_size,
                              hipStream_t stream)
{
    const float* x   = (const float*)d_in[0];
    const float* W   = (const float*)d_in[1];
    const float* ew  = (const float*)d_in[2];
    const int*   src = (const int*)d_in[3];
    const int*   dst = (const int*)d_in[4];
    float*       out = (float*)d_out;

    const int E  = in_sizes[2];
    const int N  = out_size / F_DIM;
    const int NU = N * 64;

    const int R = (N + NB - 1) / NB;                    // nodes per bucket
    int cap = (3 * E / (2 * NB) + 256) & ~255;          // ~1.5x mean, rounded
    if (cap < 512) cap = 512;
    const int cap2 = cap + 8 * R_MAX;                   // padded LDS cap
    const size_t smem_bytes = (size_t)cap2 * 6;         // f32 w + u16 src

    // ws layout (uint units): xb[NU] | segs[NB*cap*2] | g_cnt[NB]
    //   | spill_cnt[1] | align4 | spill[SPILL_CAP*4]
    size_t xb_off        = 0;
    size_t segs_off      = xb_off + (size_t)NU;
    size_t cnt_off       = segs_off + (size_t)NB * cap * 2;
    size_t spill_cnt_off = cnt_off + NB;
    size_t spill_off     = (spill_cnt_off + 1 + 3) & ~(size_t)3;
    size_t need          = (spill_off + (size_t)SPILL_CAP * 4) * 4;

    if (ws_size >= need && N >= 1 && N <= 16384 && R <= R_MAX &&
        smem_bytes <= 64 * 1024) {
        unsigned* xb        = (unsigned*)d_ws + xb_off;
        uint2*    segs      = (uint2*)((unsigned*)d_ws + segs_off);
        int*      g_cnt     = (int*)d_ws + cnt_off;
        int*      spill_cnt = (int*)d_ws + spill_cnt_off;
        int4*     spill     = (int4*)((unsigned*)d_ws + spill_off);

        const unsigned M = (unsigned)((0x100000000ULL + R - 1) / (unsigned)R);

        int NU4    = NU / 4;
        int cgrid  = (NU4 + 255) / 256;
        int s1grid = (E + TILE - 1) / TILE;
        int bgrid  = (N + R - 1) / R;

        hipMemsetAsync(g_cnt, 0, (size_t)(NB + 1) * sizeof(int), stream);
        conv_sort1_kernel<<<cgrid + s1grid, 256, 0, stream>>>(
            x, W, xb, src, dst, ew, g_cnt, spill_cnt, spill, segs,
            NU4, cgrid, E, M, R, cap);
        bucket_kernel<<<bgrid, 512, smem_bytes, stream>>>(
            xb, segs, g_cnt, spill_cnt, spill, out, N, R, cap, cap2);
    } else {
        hipMemsetAsync(out, 0, (size_t)out_size * sizeof(float), stream);
        long long tt = (long long)E * 32;
        int grid = (int)((tt + 255) / 256);
        if (grid < 1) grid = 1;
        fallback_scatter<<<grid, 256, 0, stream>>>(x, W, ew, src, dst, out, E);
    }
}